// Round 2
// 523.438 us; speedup vs baseline: 1.0218x; 1.0218x over previous
//
#include <hip/hip_runtime.h>
#include <hip/hip_bf16.h>

typedef __attribute__((ext_vector_type(8))) short short8;
typedef __attribute__((ext_vector_type(4))) float f32x4;
typedef __attribute__((ext_vector_type(16))) float f32x16;
typedef unsigned short u16;
typedef unsigned long long u64;

#define NEG_BIG (-1e30f)

#if __has_builtin(__builtin_amdgcn_exp2f)
#define EXP2(x) __builtin_amdgcn_exp2f(x)
#else
#define EXP2(x) exp2f(x)
#endif

__device__ __forceinline__ u16 f2b(float x) {
  unsigned u = __float_as_uint(x);
  u += 0x7FFFu + ((u >> 16) & 1u);   // round-to-nearest-even bf16
  return (u16)(u >> 16);
}

__device__ __forceinline__ unsigned pkbf(float a, float b) {
  union { __hip_bfloat162 h; unsigned u; } cv;
  cv.h = __float22bfloat162_rn(make_float2(a, b));
  return cv.u;
}

__device__ __forceinline__ void gl_lds16(const u16* g, u16* l) {
  __builtin_amdgcn_global_load_lds(
      (const __attribute__((address_space(1))) unsigned int*)(const void*)g,
      (__attribute__((address_space(3))) unsigned int*)(void*)l, 16, 0, 0);
}

// ---------------------------------------------------------------- casts ----
// y=0,1: hs halves -> Xb; y=2..5: Wq/Wk/Wv/Wo -> Wqb stack; y=6,7: kcache -> Kb.
__global__ __launch_bounds__(256) void cast_all(
    const float* __restrict__ hs, const float* __restrict__ Wq,
    const float* __restrict__ Wk, const float* __restrict__ Wv,
    const float* __restrict__ Wo, const float* __restrict__ kc,
    u16* __restrict__ Xb, u16* __restrict__ Wqb, u16* __restrict__ Kb) {
  const int y = blockIdx.y;
  const size_t i = (size_t)blockIdx.x * 256 + threadIdx.x;   // float4 idx in segment
  const float4* src4;
  uint2* dst;
  size_t didx;
  if (y < 2) {
    src4 = (const float4*)hs + (size_t)y * 1048576 + i;
    dst  = (uint2*)Xb;
    didx = (size_t)y * 1048576 + i;
  } else if (y < 6) {
    const float* wsrc[4] = {Wq, Wk, Wv, Wo};
    src4 = (const float4*)wsrc[y - 2] + i;
    dst  = (uint2*)Wqb;
    didx = (size_t)(y - 2) * 1048576 + i;
  } else {
    size_t g = (size_t)(y - 6) * 1048576 + i;   // global float4 idx into kcache
    src4 = (const float4*)kc + g;
    dst  = (uint2*)Kb;
    didx = (g >> 16) * 131072 + (g & 65535);    // bh stride 131072 uint2, t<2048 half
  }
  float4 v = *src4;
  uint2 pv;
  pv.x = pkbf(v.x, v.y);
  pv.y = pkbf(v.z, v.w);
  dst[didx] = pv;
}

// v_cache [B,H,2048,128] f32 -> Vt [B,H,128,4096] bf16 (t in [0,2048))
__global__ __launch_bounds__(256) void transpose_v(const float* __restrict__ src,
                                                   u16* __restrict__ dst) {
  __shared__ u16 lds[128 * 68];
  const int tid = threadIdx.x;
  const int bh = blockIdx.y;
  const int t0 = blockIdx.x * 64;
#pragma unroll
  for (int p = 0; p < 8; p++) {
    int idx = p * 256 + tid;
    int t = idx >> 5;
    int d4 = (idx & 31) * 4;
    float4 v = *(const float4*)&src[(((size_t)bh * 2048) + t0 + t) * 128 + d4];
    lds[(d4 + 0) * 68 + t] = f2b(v.x);
    lds[(d4 + 1) * 68 + t] = f2b(v.y);
    lds[(d4 + 2) * 68 + t] = f2b(v.z);
    lds[(d4 + 3) * 68 + t] = f2b(v.w);
  }
  __syncthreads();
  const int d = tid >> 1;
  const int th = (tid & 1) * 32;
  size_t obase = ((size_t)bh * 128 + d) * 4096 + t0 + th;
#pragma unroll
  for (int jb = 0; jb < 4; jb++) {
    const u16* lp = &lds[d * 68 + th + jb * 8];
    uint4 pv;
    pv.x = (unsigned)lp[0] | ((unsigned)lp[1] << 16);
    pv.y = (unsigned)lp[2] | ((unsigned)lp[3] << 16);
    pv.z = (unsigned)lp[4] | ((unsigned)lp[5] << 16);
    pv.w = (unsigned)lp[6] | ((unsigned)lp[7] << 16);
    *(uint4*)&dst[obase + jb * 8] = pv;
  }
}

// ---------------------------------------------------------------- GEMM -----
// m97 recipe: BK=64, global_load_lds width=16, rotation-swizzled unpadded LDS.
// isOut=0: B = stacked [Wq;Wk;Wv] (N=6144), scatter by z=n>>11 (Q prescaled).
// isOut=1: B = Wo (N=2048), fp32 row-major out.
#define QS (0.08838834764831845f * 1.4426950408889634f)  // 1/sqrt(128)*log2(e)
__global__ __launch_bounds__(256) void gemm_bt(
    const u16* __restrict__ A, const u16* __restrict__ Bq,
    u16* __restrict__ Qb, u16* __restrict__ Kb, u16* __restrict__ Vt,
    float* __restrict__ Cout, int isOut) {
  __shared__ u16 As[128 * 64];   // 16 KB, row=m, 128B/row, 8 chunks rotated
  __shared__ u16 Bs[128 * 64];
  const int tid = threadIdx.x;
  const int lane = tid & 63, w = tid >> 6;
  const int quad = lane >> 4, lm = lane & 15;
  const int n0 = blockIdx.x * 128, m0 = blockIdx.y * 128;
  const int wm = (w & 1) * 64, wn = (w >> 1) * 64;

  int grow[4], gch[4];
#pragma unroll
  for (int ii = 0; ii < 4; ii++) {
    int r = w * 32 + ii * 8 + (lane >> 3);
    grow[ii] = r;
    gch[ii] = ((lane & 7) - r) & 7;
  }

  f32x4 acc[4][4];
#pragma unroll
  for (int i = 0; i < 4; i++)
#pragma unroll
    for (int j = 0; j < 4; j++) acc[i][j] = (f32x4){0.f, 0.f, 0.f, 0.f};

  for (int k0 = 0; k0 < 2048; k0 += 64) {
    __syncthreads();
#pragma unroll
    for (int ii = 0; ii < 4; ii++)
      gl_lds16(A + (size_t)(m0 + grow[ii]) * 2048 + k0 + gch[ii] * 8,
               &As[(w * 32 + ii * 8) * 64]);
#pragma unroll
    for (int ii = 0; ii < 4; ii++)
      gl_lds16(Bq + (size_t)(n0 + grow[ii]) * 2048 + k0 + gch[ii] * 8,
               &Bs[(w * 32 + ii * 8) * 64]);
    __syncthreads();
    short8 af[2][4], bf[2][4];
#pragma unroll
    for (int c = 0; c < 2; c++)
#pragma unroll
      for (int i = 0; i < 4; i++) {
        int row = wm + i * 16 + lm;
        af[c][i] = *(const short8*)&As[row * 64 + ((c * 4 + quad + row) & 7) * 8];
      }
#pragma unroll
    for (int c = 0; c < 2; c++)
#pragma unroll
      for (int j = 0; j < 4; j++) {
        int row = wn + j * 16 + lm;
        bf[c][j] = *(const short8*)&Bs[row * 64 + ((c * 4 + quad + row) & 7) * 8];
      }
#pragma unroll
    for (int c = 0; c < 2; c++)
#pragma unroll
      for (int i = 0; i < 4; i++)
#pragma unroll
        for (int j = 0; j < 4; j++)
          acc[i][j] = __builtin_amdgcn_mfma_f32_16x16x32_bf16(af[c][i], bf[c][j], acc[i][j], 0, 0, 0);
  }

  if (isOut) {
#pragma unroll
    for (int i = 0; i < 4; i++)
#pragma unroll
      for (int j = 0; j < 4; j++) {
        int mrow = m0 + wm + i * 16 + quad * 4;
        int ncol = n0 + wn + j * 16 + lm;
#pragma unroll
        for (int r = 0; r < 4; r++)
          Cout[(size_t)(mrow + r) * 2048 + ncol] = acc[i][j][r];
      }
  } else {
#pragma unroll
    for (int i = 0; i < 4; i++)
#pragma unroll
      for (int j = 0; j < 4; j++) {
        int mbase = m0 + wm + i * 16 + quad * 4;
        int n = n0 + wn + j * 16 + lm;
        int b = mbase >> 11;
        int s = mbase & 2047;
        int z = n >> 11, nn = n & 2047;
        int h = nn >> 7, hd = nn & 127;
        if (z == 0) {
#pragma unroll
          for (int r = 0; r < 4; r++)
            Qb[((size_t)(b * 16 + h) * 2048 + s + r) * 128 + hd] = f2b(acc[i][j][r] * QS);
        } else if (z == 1) {
#pragma unroll
          for (int r = 0; r < 4; r++)
            Kb[((size_t)(b * 16 + h) * 4096 + 2048 + s + r) * 128 + hd] = f2b(acc[i][j][r]);
        } else {
          u64 pv = (u64)f2b(acc[i][j][0]) |
                   ((u64)f2b(acc[i][j][1]) << 16) |
                   ((u64)f2b(acc[i][j][2]) << 32) |
                   ((u64)f2b(acc[i][j][3]) << 48);
          *(u64*)&Vt[((size_t)(b * 16 + h) * 128 + hd) * 4096 + 2048 + s] = pv;
        }
      }
  }
}

// ------------------------------------------------------------ attention ----
// 32x32x16 MFMA core. 4 waves x 32 qrows = 128 qrows/wg; 512 wgs (32 bh x 16 qb),
// y->qb paired so wgs (c, c+256) sum to 98 tiles/CU.
// S^T = mfma(K, Q^T): C col = lane&31 = qrow -> softmax stats are LANE-LOCAL.
// P stays in-register: cvt_pk bf16 pairs + one shfl_xor(32) half-exchange build
// the PV B-fragments (no P LDS round-trip, no alpha broadcasts).
// PV: O^T = mfma(V^T, P^T) read from hd-major Vs (8-chunk rotation).
__global__ __launch_bounds__(256, 2) void attn_kernel(
    const u16* __restrict__ Qb, const u16* __restrict__ Kb,
    const u16* __restrict__ Vt, u16* __restrict__ attnb) {
  __shared__ u16 Ks[2][64 * 128];   // 2x16KB, row=key, 256B/row, 16 chunks rot.
  __shared__ u16 Vs[128 * 64];      // 16KB, row=hd, 128B/row, 8 chunks rot.
  const int tid = threadIdx.x;
  const int lane = tid & 63, w = tid >> 6;
  const int l31 = lane & 31, hi = lane >> 5;
  const int bh = blockIdx.x;
  const int b = bh >> 4, h = bh & 15;
  const int y = blockIdx.y;
  const int qb = (y < 8) ? y : 23 - y;       // pair (y,y+8) -> 98 tiles
  const u16* __restrict__ Qp = Qb + (size_t)bh * 2048 * 128;
  const u16* __restrict__ Kp = Kb + (size_t)bh * 4096 * 128;
  const u16* __restrict__ Vp = Vt + (size_t)bh * 128 * 4096;

  // staging offsets (chunk rotation by tile-local row)
  int koff[4], voff[4];
#pragma unroll
  for (int ii = 0; ii < 4; ii++) {
    int row = 16 * w + 4 * ii + (lane >> 4);
    koff[ii] = row * 128 + (((lane & 15) - row) & 15) * 8;
  }
#pragma unroll
  for (int jj = 0; jj < 4; jj++) {
    int row = 32 * w + 8 * jj + (lane >> 3);
    voff[jj] = row * 4096 + (((lane & 7) - row) & 7) * 8;
  }

  const int s0 = qb * 128;
  const int ntiles = 34 + 2 * qb;            // (2048 + s0 + 128)/64
  const int qa_min = 2048 + s0 + w * 32;     // wave-uniform min query pos
  const int qa = qa_min + l31;               // per-lane absolute query pos

  // Q fragments: B-frag col=q(l31), k = m*16 + hi*8 + j
  short8 qf[8];
  {
    const u16* qrow = Qp + (size_t)(s0 + w * 32 + l31) * 128 + hi * 8;
#pragma unroll
    for (int m = 0; m < 8; m++) qf[m] = *(const short8*)&qrow[m * 16];
  }

  float m_i = NEG_BIG, l_i = 0.f;
  f32x16 oaccT[4];
#pragma unroll
  for (int db = 0; db < 4; db++)
#pragma unroll
    for (int r = 0; r < 16; r++) oaccT[db][r] = 0.f;

  // prologue: stage K tile 0 into buf 0
#pragma unroll
  for (int ii = 0; ii < 4; ii++) gl_lds16(Kp + koff[ii], &Ks[0][(w * 4 + ii) * 512]);
  __syncthreads();

  for (int t = 0; t < ntiles; t++) {
    const int cur = t & 1;
    const int j0 = t * 64;
    // stage next K tile + this tile's V (drained at mid barrier)
    if (t + 1 < ntiles) {
      const u16* kg = Kp + (size_t)(j0 + 64) * 128;
#pragma unroll
      for (int ii = 0; ii < 4; ii++) gl_lds16(kg + koff[ii], &Ks[cur ^ 1][(w * 4 + ii) * 512]);
    }
    {
      const u16* vg = Vp + j0;
#pragma unroll
      for (int jj = 0; jj < 4; jj++) gl_lds16(vg + voff[jj], &Vs[(w * 4 + jj) * 512]);
    }

    // ---- S^T = K.Q^T from Ks[cur]: 2 key-blocks of 32 ----
    f32x16 sacc[2];
#pragma unroll
    for (int kb = 0; kb < 2; kb++)
#pragma unroll
      for (int r = 0; r < 16; r++) sacc[kb][r] = 0.f;
    __builtin_amdgcn_s_setprio(1);
#pragma unroll
    for (int m = 0; m < 8; m++) {
#pragma unroll
      for (int kb = 0; kb < 2; kb++) {
        int row = kb * 32 + l31;
        short8 kf = *(const short8*)&Ks[cur][row * 128 + ((2 * m + hi + row) & 15) * 8];
        sacc[kb] = __builtin_amdgcn_mfma_f32_32x32x16_bf16(kf, qf[m], sacc[kb], 0, 0, 0);
      }
    }
    __builtin_amdgcn_s_setprio(0);

    // ---- mask (only when wave-uniformly needed) ----
    // key = j0 + kb*32 + (r&3) + 8*(r>>2) + 4*hi ; qrow col = l31
    if (j0 + 63 > qa_min) {
#pragma unroll
      for (int kb = 0; kb < 2; kb++)
#pragma unroll
        for (int r = 0; r < 16; r++) {
          int key = j0 + kb * 32 + (r & 3) + 8 * (r >> 2) + 4 * hi;
          if (key > qa) sacc[kb][r] = NEG_BIG;
        }
    }

    // ---- online softmax: per-lane stats (one qrow per lane) ----
    float tm = NEG_BIG;
#pragma unroll
    for (int kb = 0; kb < 2; kb++)
#pragma unroll
      for (int r = 0; r < 16; r++) tm = fmaxf(tm, sacc[kb][r]);
    tm = fmaxf(tm, __shfl_xor(tm, 32, 64));
    float mn = fmaxf(m_i, tm);
    float al = EXP2(m_i - mn);
    m_i = mn;

    // exp2 + in-register P pack: per 16-key block tt, B-frag words via one
    // half-exchange: hi=0 keeps even-rh (pos 0-3), sends odd-rh (pos 8-11);
    // hi=1 keeps odd-rh (pos 12-15), sends even-rh (pos 4-7).
    float ts = 0.f;
    unsigned pw[4][4];
#pragma unroll
    for (int tt = 0; tt < 4; tt++) {
      int kb = tt >> 1, rb = (tt & 1) * 8;
      float p[8];
#pragma unroll
      for (int r3 = 0; r3 < 4; r3++) {
        p[r3]     = EXP2(sacc[kb][rb + r3] - mn);
        p[4 + r3] = EXP2(sacc[kb][rb + 4 + r3] - mn);
      }
      ts += ((p[0] + p[1]) + (p[2] + p[3])) + ((p[4] + p[5]) + (p[6] + p[7]));
      unsigned e0 = pkbf(p[0], p[1]), e1 = pkbf(p[2], p[3]);
      unsigned o0 = pkbf(p[4], p[5]), o1 = pkbf(p[6], p[7]);
      unsigned s0w = hi ? e0 : o0, s1w = hi ? e1 : o1;
      unsigned r0 = __shfl_xor(s0w, 32, 64), r1 = __shfl_xor(s1w, 32, 64);
      pw[tt][0] = hi ? r0 : e0;
      pw[tt][1] = hi ? r1 : e1;
      pw[tt][2] = hi ? o0 : r0;
      pw[tt][3] = hi ? o1 : r1;
    }
    ts += __shfl_xor(ts, 32, 64);
    l_i = l_i * al + ts;

    // rescale O (alpha is lane-local; skipped when all alphas == 1)
    if (__any(al < 1.0f)) {
#pragma unroll
      for (int db = 0; db < 4; db++)
#pragma unroll
        for (int r = 0; r < 16; r++) oaccT[db][r] *= al;
    }

    __syncthreads();   // drains Vs(t) [+ Ks(t+1)] staging

    // ---- O^T += V^T . P^T from Vs ----
    __builtin_amdgcn_s_setprio(1);
#pragma unroll
    for (int tt = 0; tt < 4; tt++) {
      union { unsigned u[4]; short8 s; } pa;
      pa.u[0] = pw[tt][0]; pa.u[1] = pw[tt][1];
      pa.u[2] = pw[tt][2]; pa.u[3] = pw[tt][3];
#pragma unroll
      for (int db = 0; db < 4; db++) {
        int row = db * 32 + l31;
        short8 vf = *(const short8*)&Vs[row * 64 + ((2 * tt + hi + row) & 7) * 8];
        oaccT[db] = __builtin_amdgcn_mfma_f32_32x32x16_bf16(vf, pa.s, oaccT[db], 0, 0, 0);
      }
    }
    __builtin_amdgcn_s_setprio(0);
    __syncthreads();   // WAR: Vs/Ks[cur^1] reads done before next stage
  }

  // ---- epilogue: O^T regs -> row-major attnb, packed u64 per d-group ----
  float linv = 1.0f / l_i;
  u16* orow = attnb + ((size_t)b * 2048 + (s0 + w * 32 + l31)) * 2048 + h * 128 + 4 * hi;
#pragma unroll
  for (int db = 0; db < 4; db++)
#pragma unroll
    for (int rh = 0; rh < 4; rh++) {
      u64 pv = (u64)pkbf(oaccT[db][rh * 4 + 0] * linv, oaccT[db][rh * 4 + 1] * linv) |
               ((u64)pkbf(oaccT[db][rh * 4 + 2] * linv, oaccT[db][rh * 4 + 3] * linv) << 32);
      *(u64*)&orow[db * 32 + rh * 8] = pv;
    }
}

// ---------------------------------------------------------------- launch ---
extern "C" void kernel_launch(void* const* d_in, const int* in_sizes, int n_in,
                              void* d_out, int out_size, void* d_ws, size_t ws_size,
                              hipStream_t stream) {
  const float* hs = (const float*)d_in[0];
  const float* Wq = (const float*)d_in[1];
  const float* Wk = (const float*)d_in[2];
  const float* Wv = (const float*)d_in[3];
  const float* Wo = (const float*)d_in[4];
  const float* kc = (const float*)d_in[5];
  const float* vc = (const float*)d_in[6];
  float* out = (float*)d_out;
  if (ws_size < (size_t)134217728) return;  // need 128 MiB

  char* ws = (char*)d_ws;
  u16* Xb  = (u16*)(ws);                 // 16 MiB (reused as attnb)
  u16* Wqb = (u16*)(ws + 16777216);      // stacked [Wq;Wk;Wv;Wo] bf16
  u16* Wob = Wqb + 12582912;
  u16* Kb  = (u16*)(ws + 50331648);      // [B,H,4096,128]
  u16* Vt  = (u16*)(ws + 83886080);      // [B,H,128,4096]
  u16* Qb  = (u16*)(ws + 117440512);     // [B,H,2048,128]
  u16* attnb = Xb;

  cast_all<<<dim3(4096, 8), 256, 0, stream>>>(hs, Wq, Wk, Wv, Wo, kc, Xb, Wqb, Kb);
  transpose_v<<<dim3(32, 32), 256, 0, stream>>>(vc, Vt);
  gemm_bt<<<dim3(48, 32), 256, 0, stream>>>(Xb, Wqb, Qb, Kb, Vt, nullptr, 0);
  attn_kernel<<<dim3(32, 16), 256, 0, stream>>>(Qb, Kb, Vt, attnb);
  gemm_bt<<<dim3(16, 32), 256, 0, stream>>>(attnb, Wob, nullptr, nullptr, nullptr, out, 1);
}

// Round 3
// 514.129 us; speedup vs baseline: 1.0403x; 1.0181x over previous
//
#include <hip/hip_runtime.h>
#include <hip/hip_bf16.h>

typedef __attribute__((ext_vector_type(8))) short short8;
typedef __attribute__((ext_vector_type(4))) float f32x4;
typedef __attribute__((ext_vector_type(16))) float f32x16;
typedef __attribute__((ext_vector_type(2))) unsigned uint32x2;
typedef unsigned short u16;
typedef unsigned long long u64;

#define NEG_BIG (-1e30f)

#if __has_builtin(__builtin_amdgcn_exp2f)
#define EXP2(x) __builtin_amdgcn_exp2f(x)
#else
#define EXP2(x) exp2f(x)
#endif

__device__ __forceinline__ u16 f2b(float x) {
  unsigned u = __float_as_uint(x);
  u += 0x7FFFu + ((u >> 16) & 1u);   // round-to-nearest-even bf16
  return (u16)(u >> 16);
}

__device__ __forceinline__ unsigned pkbf(float a, float b) {
  union { __hip_bfloat162 h; unsigned u; } cv;
  cv.h = __float22bfloat162_rn(make_float2(a, b));
  return cv.u;
}

__device__ __forceinline__ void gl_lds16(const u16* g, u16* l) {
  __builtin_amdgcn_global_load_lds(
      (const __attribute__((address_space(1))) unsigned int*)(const void*)g,
      (__attribute__((address_space(3))) unsigned int*)(void*)l, 16, 0, 0);
}

// ---------------------------------------------------------------- casts ----
// y=0,1: hs halves -> Xb; y=2..5: Wq/Wk/Wv/Wo -> Wqb stack; y=6,7: kcache -> Kb.
__global__ __launch_bounds__(256) void cast_all(
    const float* __restrict__ hs, const float* __restrict__ Wq,
    const float* __restrict__ Wk, const float* __restrict__ Wv,
    const float* __restrict__ Wo, const float* __restrict__ kc,
    u16* __restrict__ Xb, u16* __restrict__ Wqb, u16* __restrict__ Kb) {
  const int y = blockIdx.y;
  const size_t i = (size_t)blockIdx.x * 256 + threadIdx.x;   // float4 idx in segment
  const float4* src4;
  uint2* dst;
  size_t didx;
  if (y < 2) {
    src4 = (const float4*)hs + (size_t)y * 1048576 + i;
    dst  = (uint2*)Xb;
    didx = (size_t)y * 1048576 + i;
  } else if (y < 6) {
    const float* wsrc[4] = {Wq, Wk, Wv, Wo};
    src4 = (const float4*)wsrc[y - 2] + i;
    dst  = (uint2*)Wqb;
    didx = (size_t)(y - 2) * 1048576 + i;
  } else {
    size_t g = (size_t)(y - 6) * 1048576 + i;   // global float4 idx into kcache
    src4 = (const float4*)kc + g;
    dst  = (uint2*)Kb;
    didx = (g >> 16) * 131072 + (g & 65535);    // bh stride 131072 uint2, t<2048 half
  }
  float4 v = *src4;
  uint2 pv;
  pv.x = pkbf(v.x, v.y);
  pv.y = pkbf(v.z, v.w);
  dst[didx] = pv;
}

// v_cache [B,H,2048,128] f32 -> Vt [B,H,128,4096] bf16 (t in [0,2048))
__global__ __launch_bounds__(256) void transpose_v(const float* __restrict__ src,
                                                   u16* __restrict__ dst) {
  __shared__ u16 lds[128 * 68];
  const int tid = threadIdx.x;
  const int bh = blockIdx.y;
  const int t0 = blockIdx.x * 64;
#pragma unroll
  for (int p = 0; p < 8; p++) {
    int idx = p * 256 + tid;
    int t = idx >> 5;
    int d4 = (idx & 31) * 4;
    float4 v = *(const float4*)&src[(((size_t)bh * 2048) + t0 + t) * 128 + d4];
    lds[(d4 + 0) * 68 + t] = f2b(v.x);
    lds[(d4 + 1) * 68 + t] = f2b(v.y);
    lds[(d4 + 2) * 68 + t] = f2b(v.z);
    lds[(d4 + 3) * 68 + t] = f2b(v.w);
  }
  __syncthreads();
  const int d = tid >> 1;
  const int th = (tid & 1) * 32;
  size_t obase = ((size_t)bh * 128 + d) * 4096 + t0 + th;
#pragma unroll
  for (int jb = 0; jb < 4; jb++) {
    const u16* lp = &lds[d * 68 + th + jb * 8];
    uint4 pv;
    pv.x = (unsigned)lp[0] | ((unsigned)lp[1] << 16);
    pv.y = (unsigned)lp[2] | ((unsigned)lp[3] << 16);
    pv.z = (unsigned)lp[4] | ((unsigned)lp[5] << 16);
    pv.w = (unsigned)lp[6] | ((unsigned)lp[7] << 16);
    *(uint4*)&dst[obase + jb * 8] = pv;
  }
}

// ---------------------------------------------------------------- GEMM -----
// m97 recipe: BK=64, global_load_lds width=16, rotation-swizzled unpadded LDS.
// isOut=0: B = stacked [Wq;Wk;Wv] (N=6144), scatter by z=n>>11 (Q prescaled).
// isOut=1: B = Wo (N=2048), fp32 row-major out.
#define QS (0.08838834764831845f * 1.4426950408889634f)  // 1/sqrt(128)*log2(e)
__global__ __launch_bounds__(256) void gemm_bt(
    const u16* __restrict__ A, const u16* __restrict__ Bq,
    u16* __restrict__ Qb, u16* __restrict__ Kb, u16* __restrict__ Vt,
    float* __restrict__ Cout, int isOut) {
  __shared__ u16 As[128 * 64];   // 16 KB, row=m, 128B/row, 8 chunks rotated
  __shared__ u16 Bs[128 * 64];
  const int tid = threadIdx.x;
  const int lane = tid & 63, w = tid >> 6;
  const int quad = lane >> 4, lm = lane & 15;
  const int n0 = blockIdx.x * 128, m0 = blockIdx.y * 128;
  const int wm = (w & 1) * 64, wn = (w >> 1) * 64;

  int grow[4], gch[4];
#pragma unroll
  for (int ii = 0; ii < 4; ii++) {
    int r = w * 32 + ii * 8 + (lane >> 3);
    grow[ii] = r;
    gch[ii] = ((lane & 7) - r) & 7;
  }

  f32x4 acc[4][4];
#pragma unroll
  for (int i = 0; i < 4; i++)
#pragma unroll
    for (int j = 0; j < 4; j++) acc[i][j] = (f32x4){0.f, 0.f, 0.f, 0.f};

  for (int k0 = 0; k0 < 2048; k0 += 64) {
    __syncthreads();
#pragma unroll
    for (int ii = 0; ii < 4; ii++)
      gl_lds16(A + (size_t)(m0 + grow[ii]) * 2048 + k0 + gch[ii] * 8,
               &As[(w * 32 + ii * 8) * 64]);
#pragma unroll
    for (int ii = 0; ii < 4; ii++)
      gl_lds16(Bq + (size_t)(n0 + grow[ii]) * 2048 + k0 + gch[ii] * 8,
               &Bs[(w * 32 + ii * 8) * 64]);
    __syncthreads();
    short8 af[2][4], bf[2][4];
#pragma unroll
    for (int c = 0; c < 2; c++)
#pragma unroll
      for (int i = 0; i < 4; i++) {
        int row = wm + i * 16 + lm;
        af[c][i] = *(const short8*)&As[row * 64 + ((c * 4 + quad + row) & 7) * 8];
      }
#pragma unroll
    for (int c = 0; c < 2; c++)
#pragma unroll
      for (int j = 0; j < 4; j++) {
        int row = wn + j * 16 + lm;
        bf[c][j] = *(const short8*)&Bs[row * 64 + ((c * 4 + quad + row) & 7) * 8];
      }
#pragma unroll
    for (int c = 0; c < 2; c++)
#pragma unroll
      for (int i = 0; i < 4; i++)
#pragma unroll
        for (int j = 0; j < 4; j++)
          acc[i][j] = __builtin_amdgcn_mfma_f32_16x16x32_bf16(af[c][i], bf[c][j], acc[i][j], 0, 0, 0);
  }

  if (isOut) {
#pragma unroll
    for (int i = 0; i < 4; i++)
#pragma unroll
      for (int j = 0; j < 4; j++) {
        int mrow = m0 + wm + i * 16 + quad * 4;
        int ncol = n0 + wn + j * 16 + lm;
#pragma unroll
        for (int r = 0; r < 4; r++)
          Cout[(size_t)(mrow + r) * 2048 + ncol] = acc[i][j][r];
      }
  } else {
#pragma unroll
    for (int i = 0; i < 4; i++)
#pragma unroll
      for (int j = 0; j < 4; j++) {
        int mbase = m0 + wm + i * 16 + quad * 4;
        int n = n0 + wn + j * 16 + lm;
        int b = mbase >> 11;
        int s = mbase & 2047;
        int z = n >> 11, nn = n & 2047;
        int h = nn >> 7, hd = nn & 127;
        if (z == 0) {
#pragma unroll
          for (int r = 0; r < 4; r++)
            Qb[((size_t)(b * 16 + h) * 2048 + s + r) * 128 + hd] = f2b(acc[i][j][r] * QS);
        } else if (z == 1) {
#pragma unroll
          for (int r = 0; r < 4; r++)
            Kb[((size_t)(b * 16 + h) * 4096 + 2048 + s + r) * 128 + hd] = f2b(acc[i][j][r]);
        } else {
          u64 pv = (u64)f2b(acc[i][j][0]) |
                   ((u64)f2b(acc[i][j][1]) << 16) |
                   ((u64)f2b(acc[i][j][2]) << 32) |
                   ((u64)f2b(acc[i][j][3]) << 48);
          *(u64*)&Vt[((size_t)(b * 16 + h) * 128 + hd) * 4096 + 2048 + s] = pv;
        }
      }
  }
}

// ------------------------------------------------------------ attention ----
// 32x32x16 MFMA core; 4 waves x 32 qrows; 512 wgs (32 bh x 16 qb), y->qb paired
// so wgs (c, c+256) sum to 98 tiles/CU.
// K AND V double-buffered -> ONE barrier per tile: stage(t+1) into buf[nxt],
// compute QK/softmax/PV entirely from buf[cur], barrier at tile end (WAR for
// buf[cur] which becomes the staging target at t+1; visibility via the
// implicit vmcnt(0) drain each wave does at the barrier, a full tile after
// the loads were issued).
// S^T = mfma(K, Q^T): C col = lane&31 = qrow -> softmax stats LANE-LOCAL.
// P in-register: cvt_pk pairs + permlane32_swap (a.hi <-> b.lo) builds both
// PV B-frag words per swap — no LDS round-trip, no cndmask selects.
__global__ __launch_bounds__(256, 2) void attn_kernel(
    const u16* __restrict__ Qb, const u16* __restrict__ Kb,
    const u16* __restrict__ Vt, u16* __restrict__ attnb) {
  __shared__ u16 Ks[2][64 * 128];   // 2x16KB, row=key, 256B/row, 16 chunks rot.
  __shared__ u16 Vs[2][128 * 64];   // 2x16KB, row=hd, 128B/row, 8 chunks rot.
  const int tid = threadIdx.x;
  const int lane = tid & 63, w = tid >> 6;
  const int l31 = lane & 31, hi = lane >> 5;
  const int bh = blockIdx.x;
  const int b = bh >> 4, h = bh & 15;
  const int y = blockIdx.y;
  const int qb = (y < 8) ? y : 23 - y;       // pair (y,y+8) -> 98 tiles
  const u16* __restrict__ Qp = Qb + (size_t)bh * 2048 * 128;
  const u16* __restrict__ Kp = Kb + (size_t)bh * 4096 * 128;
  const u16* __restrict__ Vp = Vt + (size_t)bh * 128 * 4096;

  // staging offsets (chunk rotation by tile-local row)
  int koff[4], voff[4];
#pragma unroll
  for (int ii = 0; ii < 4; ii++) {
    int row = 16 * w + 4 * ii + (lane >> 4);
    koff[ii] = row * 128 + (((lane & 15) - row) & 15) * 8;
  }
#pragma unroll
  for (int jj = 0; jj < 4; jj++) {
    int row = 32 * w + 8 * jj + (lane >> 3);
    voff[jj] = row * 4096 + (((lane & 7) - row) & 7) * 8;
  }

  const int s0 = qb * 128;
  const int ntiles = 34 + 2 * qb;            // (2048 + s0 + 128)/64
  const int qa_min = 2048 + s0 + w * 32;     // wave-uniform min query pos
  const int qa = qa_min + l31;               // per-lane absolute query pos

  // Q fragments: B-frag col=q(l31), k = m*16 + hi*8 + j
  short8 qf[8];
  {
    const u16* qrow = Qp + (size_t)(s0 + w * 32 + l31) * 128 + hi * 8;
#pragma unroll
    for (int m = 0; m < 8; m++) qf[m] = *(const short8*)&qrow[m * 16];
  }

  float m_i = NEG_BIG, l_i = 0.f;
  f32x16 oaccT[4];
#pragma unroll
  for (int db = 0; db < 4; db++)
#pragma unroll
    for (int r = 0; r < 16; r++) oaccT[db][r] = 0.f;

  // prologue: stage K(0), V(0) into buf 0
#pragma unroll
  for (int ii = 0; ii < 4; ii++) gl_lds16(Kp + koff[ii], &Ks[0][(w * 4 + ii) * 512]);
#pragma unroll
  for (int jj = 0; jj < 4; jj++) gl_lds16(Vp + voff[jj], &Vs[0][(w * 4 + jj) * 512]);
  __syncthreads();

  for (int t = 0; t < ntiles; t++) {
    const int cur = t & 1;
    const int j0 = t * 64;
    // stage NEXT tile's K and V into buf[cur^1]
    if (t + 1 < ntiles) {
      const u16* kg = Kp + (size_t)(j0 + 64) * 128;
      const u16* vg = Vp + j0 + 64;
#pragma unroll
      for (int ii = 0; ii < 4; ii++) gl_lds16(kg + koff[ii], &Ks[cur ^ 1][(w * 4 + ii) * 512]);
#pragma unroll
      for (int jj = 0; jj < 4; jj++) gl_lds16(vg + voff[jj], &Vs[cur ^ 1][(w * 4 + jj) * 512]);
    }

    // ---- S^T = K.Q^T from Ks[cur]: 2 key-blocks of 32 ----
    f32x16 sacc[2];
#pragma unroll
    for (int kb = 0; kb < 2; kb++)
#pragma unroll
      for (int r = 0; r < 16; r++) sacc[kb][r] = 0.f;
    __builtin_amdgcn_s_setprio(1);
#pragma unroll
    for (int m = 0; m < 8; m++) {
#pragma unroll
      for (int kb = 0; kb < 2; kb++) {
        int row = kb * 32 + l31;
        short8 kf = *(const short8*)&Ks[cur][row * 128 + ((2 * m + hi + row) & 15) * 8];
        sacc[kb] = __builtin_amdgcn_mfma_f32_32x32x16_bf16(kf, qf[m], sacc[kb], 0, 0, 0);
      }
    }
    __builtin_amdgcn_s_setprio(0);

    // ---- mask (only when wave-uniformly needed) ----
    // key = j0 + kb*32 + (r&3) + 8*(r>>2) + 4*hi ; qrow col = l31
    if (j0 + 63 > qa_min) {
#pragma unroll
      for (int kb = 0; kb < 2; kb++)
#pragma unroll
        for (int r = 0; r < 16; r++) {
          int key = j0 + kb * 32 + (r & 3) + 8 * (r >> 2) + 4 * hi;
          if (key > qa) sacc[kb][r] = NEG_BIG;
        }
    }

    // ---- online softmax: per-lane stats (one qrow per lane) ----
    float tm = NEG_BIG;
#pragma unroll
    for (int kb = 0; kb < 2; kb++)
#pragma unroll
      for (int r = 0; r < 16; r++) tm = fmaxf(tm, sacc[kb][r]);
    tm = fmaxf(tm, __shfl_xor(tm, 32, 64));
    float mn = fmaxf(m_i, tm);
    float al = EXP2(m_i - mn);
    m_i = mn;

    // exp2 + in-register P pack. Per 16-key block tt, lane holds keys
    // {0..3}+4hi (e-words) and {8..11}+4hi (o-words). permlane32_swap(e,o)
    // exchanges e.hi with o.lo -> returns {w_lo, w_mid} B-frag words.
    float ts = 0.f;
    unsigned pw[4][4];
#pragma unroll
    for (int tt = 0; tt < 4; tt++) {
      int kb = tt >> 1, rb = (tt & 1) * 8;
      float p[8];
#pragma unroll
      for (int r3 = 0; r3 < 4; r3++) {
        p[r3]     = EXP2(sacc[kb][rb + r3] - mn);
        p[4 + r3] = EXP2(sacc[kb][rb + 4 + r3] - mn);
      }
      ts += ((p[0] + p[1]) + (p[2] + p[3])) + ((p[4] + p[5]) + (p[6] + p[7]));
      unsigned e0 = pkbf(p[0], p[1]), e1 = pkbf(p[2], p[3]);
      unsigned o0 = pkbf(p[4], p[5]), o1 = pkbf(p[6], p[7]);
      uint32x2 r0 = __builtin_amdgcn_permlane32_swap(e0, o0, 0, 0);  // {w0, w2}
      uint32x2 r1 = __builtin_amdgcn_permlane32_swap(e1, o1, 0, 0);  // {w1, w3}
      pw[tt][0] = r0.x;
      pw[tt][1] = r1.x;
      pw[tt][2] = r0.y;
      pw[tt][3] = r1.y;
    }
    ts += __shfl_xor(ts, 32, 64);
    l_i = l_i * al + ts;

    // rescale O (alpha is lane-local; skipped when all alphas == 1)
    if (__any(al < 1.0f)) {
#pragma unroll
      for (int db = 0; db < 4; db++)
#pragma unroll
        for (int r = 0; r < 16; r++) oaccT[db][r] *= al;
    }

    // ---- O^T += V^T . P^T from Vs[cur] ----
    __builtin_amdgcn_s_setprio(1);
#pragma unroll
    for (int tt = 0; tt < 4; tt++) {
      union { unsigned u[4]; short8 s; } pa;
      pa.u[0] = pw[tt][0]; pa.u[1] = pw[tt][1];
      pa.u[2] = pw[tt][2]; pa.u[3] = pw[tt][3];
#pragma unroll
      for (int db = 0; db < 4; db++) {
        int row = db * 32 + l31;
        short8 vf = *(const short8*)&Vs[cur][row * 64 + ((2 * tt + hi + row) & 7) * 8];
        oaccT[db] = __builtin_amdgcn_mfma_f32_32x32x16_bf16(vf, pa.s, oaccT[db], 0, 0, 0);
      }
    }
    __builtin_amdgcn_s_setprio(0);
    __syncthreads();   // single per-tile barrier: WAR on buf[cur] + visibility
  }

  // ---- epilogue: O^T regs -> row-major attnb, packed u64 per d-group ----
  float linv = 1.0f / l_i;
  u16* orow = attnb + ((size_t)b * 2048 + (s0 + w * 32 + l31)) * 2048 + h * 128 + 4 * hi;
#pragma unroll
  for (int db = 0; db < 4; db++)
#pragma unroll
    for (int rh = 0; rh < 4; rh++) {
      u64 pv = (u64)pkbf(oaccT[db][rh * 4 + 0] * linv, oaccT[db][rh * 4 + 1] * linv) |
               ((u64)pkbf(oaccT[db][rh * 4 + 2] * linv, oaccT[db][rh * 4 + 3] * linv) << 32);
      *(u64*)&orow[db * 32 + rh * 8] = pv;
    }
}

// ---------------------------------------------------------------- launch ---
extern "C" void kernel_launch(void* const* d_in, const int* in_sizes, int n_in,
                              void* d_out, int out_size, void* d_ws, size_t ws_size,
                              hipStream_t stream) {
  const float* hs = (const float*)d_in[0];
  const float* Wq = (const float*)d_in[1];
  const float* Wk = (const float*)d_in[2];
  const float* Wv = (const float*)d_in[3];
  const float* Wo = (const float*)d_in[4];
  const float* kc = (const float*)d_in[5];
  const float* vc = (const float*)d_in[6];
  float* out = (float*)d_out;
  if (ws_size < (size_t)134217728) return;  // need 128 MiB

  char* ws = (char*)d_ws;
  u16* Xb  = (u16*)(ws);                 // 16 MiB (reused as attnb)
  u16* Wqb = (u16*)(ws + 16777216);      // stacked [Wq;Wk;Wv;Wo] bf16
  u16* Wob = Wqb + 12582912;
  u16* Kb  = (u16*)(ws + 50331648);      // [B,H,4096,128]
  u16* Vt  = (u16*)(ws + 83886080);      // [B,H,128,4096]
  u16* Qb  = (u16*)(ws + 117440512);     // [B,H,2048,128]
  u16* attnb = Xb;

  cast_all<<<dim3(4096, 8), 256, 0, stream>>>(hs, Wq, Wk, Wv, Wo, kc, Xb, Wqb, Kb);
  transpose_v<<<dim3(32, 32), 256, 0, stream>>>(vc, Vt);
  gemm_bt<<<dim3(48, 32), 256, 0, stream>>>(Xb, Wqb, Qb, Kb, Vt, nullptr, 0);
  attn_kernel<<<dim3(32, 16), 256, 0, stream>>>(Qb, Kb, Vt, attnb);
  gemm_bt<<<dim3(16, 32), 256, 0, stream>>>(attnb, Wob, nullptr, nullptr, nullptr, out, 1);
}